// Round 9
// baseline (141.507 us; speedup 1.0000x reference)
//
#include <hip/hip_runtime.h>
#include <hip/hip_bf16.h>

typedef __bf16 bf16x8 __attribute__((ext_vector_type(8)));
typedef __bf16 bf16x2 __attribute__((ext_vector_type(2)));
typedef float  f32x16 __attribute__((ext_vector_type(16)));
typedef float  f32x4  __attribute__((ext_vector_type(4)));

#define HD   2048   // H*D floats per token row
#define DH   128
#define KVT  64     // kv tile
#define NIT  32     // 2048/64

// ---------------------------------------------------------------------------
// Single-pass attention, 2 independent blocks/CU for phase diversity.
// 256 thr = 4 warps x 32 q = 128 q/block; grid 256 = 16 qblk x 16 h (b%8=XCD,
// heads {x,x+8} per XCD -> KV slice L2-resident). LDS 64KB/block -> 2 blocks
// co-resident; independent barriers let block A's MFMA overlap block B's
// VALU/LDS phases (R5/R7 showed intra-block waves are barrier-phase-locked).
// No kv-split, no workspace, no combine: direct normalized O write.
//
// V layout: vtlds[dv][64] bf16 with kv-permuted positions (bit2<->bit3 within
// each 16-block) + depth-8 granule XOR (granule ^= dv&7): each PV A-fragment
// is ONE conflict-free ds_read_b128 (R7 used 2x b64 + assembly movs).
// K layout: rows [64][128] with granule ^= row&7 (R7-proven).
// Staging schedule (register peak control): QK -> kload(t+1) -> softmax-max
// -> kwrite -> vload(t+1) -> exp/pf -> PV -> vwrite -> barrier.
// ---------------------------------------------------------------------------
__global__ __launch_bounds__(256, 2)
void fmha_kern(const float* __restrict__ Qg, const float* __restrict__ Kg,
               const float* __restrict__ Vg, float* __restrict__ Og)
{
    __shared__ __align__(16) __bf16 klds[2][KVT * 128];   // 16KB per buf
    __shared__ __align__(16) __bf16 vtlds[2][DH * KVT];   // 16KB per buf

    const int tid  = threadIdx.x;
    const int lane = tid & 63;
    const int wrp  = tid >> 6;      // 0..3
    const int g    = lane >> 5;
    const int l31  = lane & 31;

    const int b    = blockIdx.x;
    const int h    = b & 15;        // XCD = b%8 -> heads {x, x+8}
    const int qblk = b >> 4;        // 0..15

    const float qscale = 1.4426950408889634f * 0.08838834764831845f; // log2(e)/sqrt(128)
    const int q = qblk * 128 + wrp * 32 + l31;

    // ---- Q fragments (B-operand of QK^T): lane=q-row, d = j*16 + 8g + e
    bf16x8 qf[8];
    {
        const float* qrow = Qg + (size_t)q * HD + h * DH;
        #pragma unroll
        for (int j = 0; j < 8; ++j) {
            f32x4 a = *(const f32x4*)(qrow + j * 16 + 8 * g);
            f32x4 c = *(const f32x4*)(qrow + j * 16 + 8 * g + 4);
            bf16x8 f;
            f[0] = (__bf16)(a[0] * qscale); f[1] = (__bf16)(a[1] * qscale);
            f[2] = (__bf16)(a[2] * qscale); f[3] = (__bf16)(a[3] * qscale);
            f[4] = (__bf16)(c[0] * qscale); f[5] = (__bf16)(c[1] * qscale);
            f[6] = (__bf16)(c[2] * qscale); f[7] = (__bf16)(c[3] * qscale);
            qf[j] = f;
        }
    }

    // ---- staging split across 256 threads
    const int krow = tid >> 2;            // 0..63 (kv row)
    const int kc4  = (tid & 3) * 32;      // col base (floats); 4 lanes = 64B contig
    const int kvp  = tid & 31;            // kv pair (2kvp, 2kvp+1)
    const int vdv0 = (tid >> 5) * 16;     // dv base 0..112

    // V storage position for kv k: swap bits 2<->3 within each 16-block
    const int kk   = 2 * kvp;
    const int vpos = (kk & 3) + (((kk >> 3) & 1) << 2) + (((kk >> 2) & 1) << 3) + (kk & ~15);
    const int vgr  = vpos >> 3;           // granule 0..7
    const int vlo  = vpos & 7;            // even

    const float* kbase = Kg + (size_t)h * DH;
    const float* vbase = Vg + (size_t)h * DH;

    f32x4 kreg[8], vreg[8];   // disjoint lifetimes (kreg: QK->kwrite, vreg: vload->vwrite)

    auto kload = [&](int t) {
        const float* kp = kbase + (size_t)(t * KVT + krow) * HD + kc4;
        #pragma unroll
        for (int j = 0; j < 8; ++j) kreg[j] = *(const f32x4*)(kp + 4 * j);
    };
    auto kwrite = [&](int buf) {
        const int key = krow & 7;
        #pragma unroll
        for (int j8 = 0; j8 < 4; ++j8) {
            f32x4 a = kreg[2 * j8], c = kreg[2 * j8 + 1];
            bf16x8 w;
            w[0]=(__bf16)a[0]; w[1]=(__bf16)a[1]; w[2]=(__bf16)a[2]; w[3]=(__bf16)a[3];
            w[4]=(__bf16)c[0]; w[5]=(__bf16)c[1]; w[6]=(__bf16)c[2]; w[7]=(__bf16)c[3];
            const int gr = ((kc4 >> 3) + j8) ^ key;
            *(bf16x8*)&klds[buf][krow * 128 + (gr << 3)] = w;
        }
    };
    auto vload = [&](int t) {
        const float* vp = vbase + (size_t)(t * KVT + 2 * kvp) * HD + vdv0;
        #pragma unroll
        for (int j = 0; j < 4; ++j) {
            vreg[j]     = *(const f32x4*)(vp + 4 * j);        // kv 2kvp
            vreg[4 + j] = *(const f32x4*)(vp + HD + 4 * j);   // kv 2kvp+1
        }
    };
    auto vwrite = [&](int buf) {
        #pragma unroll
        for (int e = 0; e < 16; ++e) {
            const int dv = vdv0 + e;
            bf16x2 w;
            w[0] = (__bf16)vreg[e >> 2][e & 3];
            w[1] = (__bf16)vreg[4 + (e >> 2)][e & 3];
            *(bf16x2*)&vtlds[buf][dv * 64 + (((vgr ^ (dv & 7)) << 3) + vlo)] = w;
        }
    };

    auto bsync = []() {
        asm volatile("s_waitcnt lgkmcnt(0)" ::: "memory");
        __builtin_amdgcn_s_barrier();
    };

    float mrun = -1e30f, lrun = 0.0f;
    f32x16 o0, o1, o2, o3;
    #pragma unroll
    for (int r = 0; r < 16; ++r) { o0[r] = 0.f; o1[r] = 0.f; o2[r] = 0.f; o3[r] = 0.f; }

    // prologue: tile 0 -> buf0
    kload(0); kwrite(0);
    vload(0); vwrite(0);
    bsync();

    const int key = l31 & 7;

    #pragma unroll 2
    for (int tt = 0; tt < NIT; ++tt) {
        const int cur = tt & 1;

        // ---- QK^T (swapped): S^T[kv][q], 2 chained 32-kv accumulators
        f32x16 s0, s1;
        #pragma unroll
        for (int r = 0; r < 16; ++r) { s0[r] = 0.f; s1[r] = 0.f; }
        __builtin_amdgcn_s_setprio(1);
        #pragma unroll
        for (int j = 0; j < 8; ++j) {
            const int gcol = (((2 * j + g) ^ key) << 3);
            bf16x8 k0 = *(const bf16x8*)&klds[cur][l31 * 128 + gcol];
            s0 = __builtin_amdgcn_mfma_f32_32x32x16_bf16(k0, qf[j], s0, 0, 0, 0);
            bf16x8 k1 = *(const bf16x8*)&klds[cur][(32 + l31) * 128 + gcol];
            s1 = __builtin_amdgcn_mfma_f32_32x32x16_bf16(k1, qf[j], s1, 0, 0, 0);
        }
        __builtin_amdgcn_s_setprio(0);

        if (tt + 1 < NIT) kload(tt + 1);   // issue K loads; softmax covers latency

        // ---- online softmax max, T13 defer-max (base-2, P <= 2^8)
        float m16[8];
        #pragma unroll
        for (int r = 0; r < 8; ++r)
            m16[r] = fmaxf(fmaxf(s0[r], s0[r + 8]), fmaxf(s1[r], s1[r + 8]));
        float tmax = fmaxf(fmaxf(fmaxf(m16[0], m16[4]), fmaxf(m16[1], m16[5])),
                           fmaxf(fmaxf(m16[2], m16[6]), fmaxf(m16[3], m16[7])));
        tmax = fmaxf(tmax, __shfl_xor(tmax, 32, 64));

        if (__any(tmax > mrun + 8.0f)) {
            const float mnew  = fmaxf(mrun, tmax);
            const float alpha = __builtin_amdgcn_exp2f(mrun - mnew);
            lrun *= alpha;
            #pragma unroll
            for (int r = 0; r < 16; ++r) { o0[r]*=alpha; o1[r]*=alpha; o2[r]*=alpha; o3[r]*=alpha; }
            mrun = mnew;
        }

        if (tt + 1 < NIT) { kwrite(cur ^ 1); vload(tt + 1); }  // K->LDS, issue V loads

        // ---- exp in place; P sums
        #pragma unroll
        for (int r = 0; r < 16; ++r) {
            s0[r] = __builtin_amdgcn_exp2f(s0[r] - mrun);
            s1[r] = __builtin_amdgcn_exp2f(s1[r] - mrun);
        }
        float ps = 0.f;
        #pragma unroll
        for (int r = 0; r < 16; ++r) ps += s0[r] + s1[r];
        lrun += ps;

        // P -> bf16 (S^T C/D reg order == PV B-slot order, verified bijection)
        bf16x8 pf0, pf1, pf2, pf3;
        #pragma unroll
        for (int e = 0; e < 8; ++e) {
            pf0[e] = (__bf16)s0[e]; pf1[e] = (__bf16)s0[8 + e];
            pf2[e] = (__bf16)s1[e]; pf3[e] = (__bf16)s1[8 + e];
        }

        // ---- PV: O^T[dv][q] += V^T[dv][kv] * P^T[kv][q]; single b128 A-frag reads
        __builtin_amdgcn_s_setprio(1);
        #pragma unroll
        for (int bb = 0; bb < 4; ++bb) {
            const __bf16* vb = &vtlds[cur][(bb * 32 + l31) * 64];
            f32x16& oo = (bb == 0) ? o0 : (bb == 1) ? o1 : (bb == 2) ? o2 : o3;
            bf16x8 va;
            va = *(const bf16x8*)(vb + (((0 + g) ^ key) << 3));
            oo = __builtin_amdgcn_mfma_f32_32x32x16_bf16(va, pf0, oo, 0, 0, 0);
            va = *(const bf16x8*)(vb + (((2 + g) ^ key) << 3));
            oo = __builtin_amdgcn_mfma_f32_32x32x16_bf16(va, pf1, oo, 0, 0, 0);
            va = *(const bf16x8*)(vb + (((4 + g) ^ key) << 3));
            oo = __builtin_amdgcn_mfma_f32_32x32x16_bf16(va, pf2, oo, 0, 0, 0);
            va = *(const bf16x8*)(vb + (((6 + g) ^ key) << 3));
            oo = __builtin_amdgcn_mfma_f32_32x32x16_bf16(va, pf3, oo, 0, 0, 0);
        }
        __builtin_amdgcn_s_setprio(0);

        if (tt + 1 < NIT) {
            vwrite(cur ^ 1);
            bsync();
        }
    }

    // ---- epilogue: normalize, direct store
    const float ltot = lrun + __shfl_xor(lrun, 32, 64);
    const float inv  = 1.0f / ltot;
    float* orow = Og + ((size_t)q * 16 + h) * 128;
    #pragma unroll
    for (int bb = 0; bb < 4; ++bb) {
        const f32x16& oo = (bb == 0) ? o0 : (bb == 1) ? o1 : (bb == 2) ? o2 : o3;
        #pragma unroll
        for (int jj = 0; jj < 4; ++jj) {
            f32x4 v;
            v[0] = oo[4*jj+0] * inv; v[1] = oo[4*jj+1] * inv;
            v[2] = oo[4*jj+2] * inv; v[3] = oo[4*jj+3] * inv;
            *(f32x4*)(orow + bb * 32 + 8 * jj + 4 * g) = v;
        }
    }
}

extern "C" void kernel_launch(void* const* d_in, const int* in_sizes, int n_in,
                              void* d_out, int out_size, void* d_ws, size_t ws_size,
                              hipStream_t stream) {
    const float* Q = (const float*)d_in[0];
    const float* K = (const float*)d_in[1];
    const float* V = (const float*)d_in[2];
    float* O = (float*)d_out;
    hipLaunchKernelGGL(fmha_kern, dim3(256), dim3(256), 0, stream, Q, K, V, O);
}

// Round 10
// 74.776 us; speedup vs baseline: 1.8924x; 1.8924x over previous
//
#include <hip/hip_runtime.h>
#include <hip/hip_bf16.h>

typedef __bf16 bf16x8 __attribute__((ext_vector_type(8)));
typedef __bf16 bf16x4 __attribute__((ext_vector_type(4)));
typedef float  f32x16 __attribute__((ext_vector_type(16)));
typedef float  f32x4  __attribute__((ext_vector_type(4)));

#define HD     2048   // H*D floats per token row
#define DH     128
#define KVT    64     // kv tile rows
#define NCH    16     // tiles per split half (1024/64)
#define NSPLIT 2
#define NROWS  32768  // Lq*H
#define TILE_ELEMS 8192    // 64x128 bf16 (16 KB)

// global_load_lds: LDS dest = wave-uniform base + lane*16 (HW); global src per-lane.
__device__ __forceinline__ void glds16(const void* g, void* l) {
    typedef const __attribute__((address_space(1))) void g_as_t;
    typedef __attribute__((address_space(3))) void l_as_t;
    __builtin_amdgcn_global_load_lds((g_as_t*)g, (l_as_t*)l, 16, 0, 0);
}

// ---------------------------------------------------------------------------
// Prepass 1: K[kv][h][d] fp32 -> wsK tiles [h][T=kv/64][row=kv&63][swz cols]
// bf16. Granule c8 (16B unit, 0..15) stored at c8 ^ (row&15); main kernel
// reads with the same XOR (rule 21: pre-swizzled source + linear glds +
// swizzled read). 2048 blocks (one kv row) x 256 thr (16 h x 16 c8).
// ---------------------------------------------------------------------------
__global__ __launch_bounds__(256, 8)
void prep_k(const float* __restrict__ Kg, __bf16* __restrict__ wsK)
{
    const int kv = blockIdx.x;
    const int t  = threadIdx.x;
    const int h  = t >> 4, c8 = t & 15;
    const float* src = Kg + (size_t)kv * HD + h * DH + c8 * 8;
    f32x4 a = *(const f32x4*)(src);
    f32x4 b = *(const f32x4*)(src + 4);
    bf16x8 o;
    o[0]=(__bf16)a[0]; o[1]=(__bf16)a[1]; o[2]=(__bf16)a[2]; o[3]=(__bf16)a[3];
    o[4]=(__bf16)b[0]; o[5]=(__bf16)b[1]; o[6]=(__bf16)b[2]; o[7]=(__bf16)b[3];
    __bf16* dst = wsK + ((size_t)(h * 32 + (kv >> 6)) * TILE_ELEMS)
                      + (kv & 63) * 128 + ((c8 ^ (kv & 15)) << 3);
    *(bf16x8*)dst = o;
}

// ---------------------------------------------------------------------------
// Prepass 2: V[kv][h][dv] fp32 -> wsV tiles [h][T][dv=0..127][kv-swz 0..63]
// bf16 via 32x32 LDS transpose. kv-granule kg (0..7) stored at kg ^ (dv&7).
// grid b = h*256 + kvb*4 + dvb  (kvb = global 32-kv block 0..63).
// ---------------------------------------------------------------------------
__global__ __launch_bounds__(256, 4)
void prep_vt(const float* __restrict__ Vg, __bf16* __restrict__ wsV)
{
    __shared__ float tile[32][33];
    const int b = blockIdx.x;
    const int dvb = b & 3, kvb = (b >> 2) & 63, h = b >> 8;
    const int t = threadIdx.x;
    {
        const int kvl = t >> 3, dv4 = (t & 7) * 4;
        f32x4 v = *(const f32x4*)(Vg + (size_t)(kvb * 32 + kvl) * HD + h * DH + dvb * 32 + dv4);
        tile[kvl][dv4 + 0] = v[0]; tile[kvl][dv4 + 1] = v[1];
        tile[kvl][dv4 + 2] = v[2]; tile[kvl][dv4 + 3] = v[3];
    }
    __syncthreads();
    {
        const int dvl = t >> 3, kv4 = (t & 7) * 4;
        const int dv   = dvb * 32 + dvl;
        const int T    = kvb >> 1;
        const int kloc = (kvb & 1) * 32 + kv4;   // 0..63, aligned 4
        const int kg   = kloc >> 3;
        bf16x4 o;
        o[0] = (__bf16)tile[kv4 + 0][dvl]; o[1] = (__bf16)tile[kv4 + 1][dvl];
        o[2] = (__bf16)tile[kv4 + 2][dvl]; o[3] = (__bf16)tile[kv4 + 3][dvl];
        __bf16* dst = wsV + ((size_t)(h * 32 + T) * TILE_ELEMS)
                          + dv * 64 + (((kg ^ (dv & 7)) << 3) + (kloc & 7));
        *(bf16x4*)dst = o;
    }
}

// ---------------------------------------------------------------------------
// Main attention: 256 thr = 4 warps x 32 q = 128 q/block; KVT=64, 16 iters;
// grid 512 = 16 qblk x (16 h x 2 sp). LDS 64KB/block, VGPR<=256 (256,2)
// -> 2 blocks/CU co-resident with INDEPENDENT barriers: block A's MFMA
// overlaps block B's softmax/LDS phases (R5/R7: intra-block waves are
// barrier-phase-locked; R9's 1-block grid couldn't test this).
// Staging = 8 glds instr per thread-free 32KB copy (no cvt, no ds_write,
// no staging regs). vmcnt(0)+lgkmcnt(0)+barrier once per iter, glds issued
// at top of iter -> full-iteration cover. grp%8 = XCD.
// ---------------------------------------------------------------------------
__global__ __launch_bounds__(256, 2)
void fmha_main(const float* __restrict__ Qg,
               const __bf16* __restrict__ wsK, const __bf16* __restrict__ wsV,
               float* __restrict__ wsO, float* __restrict__ wsML)
{
    __shared__ __align__(16) __bf16 klds[2][TILE_ELEMS];   // 16KB each
    __shared__ __align__(16) __bf16 vlds[2][TILE_ELEMS];   // 16KB each

    const int tid  = threadIdx.x;
    const int lane = tid & 63;
    const int wrp  = tid >> 6;
    const int g    = lane >> 5;
    const int l31  = lane & 31;

    const int b    = blockIdx.x;
    const int grp  = b & 31;          // XCD = grp%8; qblk-siblings share KV in L2
    const int qblk = b >> 5;
    const int h    = grp >> 1;
    const int sp   = grp & 1;
    const int T0   = sp * NCH;

    const float qscale = 1.4426950408889634f * 0.08838834764831845f; // log2(e)/sqrt(128)
    const int q = qblk * 128 + wrp * 32 + l31;

    // ---- Q fragments (B-operand of QK^T): lane=q-row, d = j*16 + 8g + e
    bf16x8 qf[8];
    {
        const float* qrow = Qg + (size_t)q * HD + h * DH;
        #pragma unroll
        for (int j = 0; j < 8; ++j) {
            f32x4 a = *(const f32x4*)(qrow + j * 16 + 8 * g);
            f32x4 c = *(const f32x4*)(qrow + j * 16 + 8 * g + 4);
            bf16x8 f;
            f[0] = (__bf16)(a[0] * qscale); f[1] = (__bf16)(a[1] * qscale);
            f[2] = (__bf16)(a[2] * qscale); f[3] = (__bf16)(a[3] * qscale);
            f[4] = (__bf16)(c[0] * qscale); f[5] = (__bf16)(c[1] * qscale);
            f[6] = (__bf16)(c[2] * qscale); f[7] = (__bf16)(c[3] * qscale);
            qf[j] = f;
        }
    }

    // ---- staging: 4 waves x 4 chunks of 1KB per 16KB tile, K and V
    auto stage = [&](int T, int buf) {
        const char* kt = (const char*)(wsK + (size_t)(h * 32 + T) * TILE_ELEMS) + lane * 16;
        const char* vt = (const char*)(wsV + (size_t)(h * 32 + T) * TILE_ELEMS) + lane * 16;
        char* kl = (char*)&klds[buf][0];
        char* vl = (char*)&vlds[buf][0];
        #pragma unroll
        for (int i = 0; i < 4; ++i) {
            const int c = (i * 4 + wrp) * 1024;
            glds16(kt + c, kl + c);
            glds16(vt + c, vl + c);
        }
    };

    auto sync_all = []() {
        asm volatile("s_waitcnt vmcnt(0) lgkmcnt(0)" ::: "memory");
        __builtin_amdgcn_s_barrier();
    };

    float mrun = -1e30f, lrun = 0.0f;
    f32x16 o0, o1, o2, o3;
    #pragma unroll
    for (int r = 0; r < 16; ++r) { o0[r] = 0.f; o1[r] = 0.f; o2[r] = 0.f; o3[r] = 0.f; }

    stage(T0, 0);
    sync_all();

    const int ksw  = l31 & 15;   // K granule key: rows l31 / 32+l31 share it
    const int vkey = l31 & 7;    // V granule key: rows bb*32+l31 share it

    #pragma unroll 2
    for (int tt = 0; tt < NCH; ++tt) {
        const int cur = tt & 1;
        if (tt + 1 < NCH) stage(T0 + tt + 1, cur ^ 1);   // issue-early, full-iter cover

        // ---- QK^T (swapped): S^T[kv][q], 2 chained 32-kv accumulators
        f32x16 s0, s1;
        #pragma unroll
        for (int r = 0; r < 16; ++r) { s0[r] = 0.f; s1[r] = 0.f; }
        __builtin_amdgcn_s_setprio(1);
        #pragma unroll
        for (int j = 0; j < 8; ++j) {
            const int gcol = ((2 * j + g) ^ ksw) << 3;
            bf16x8 k0 = *(const bf16x8*)&klds[cur][l31 * 128 + gcol];
            s0 = __builtin_amdgcn_mfma_f32_32x32x16_bf16(k0, qf[j], s0, 0, 0, 0);
            bf16x8 k1 = *(const bf16x8*)&klds[cur][(32 + l31) * 128 + gcol];
            s1 = __builtin_amdgcn_mfma_f32_32x32x16_bf16(k1, qf[j], s1, 0, 0, 0);
        }
        __builtin_amdgcn_s_setprio(0);

        // ---- online softmax, T13 defer-max (base-2, P <= 2^8)
        float m16[8];
        #pragma unroll
        for (int r = 0; r < 8; ++r)
            m16[r] = fmaxf(fmaxf(s0[r], s0[r + 8]), fmaxf(s1[r], s1[r + 8]));
        float tmax = fmaxf(fmaxf(fmaxf(m16[0], m16[4]), fmaxf(m16[1], m16[5])),
                           fmaxf(fmaxf(m16[2], m16[6]), fmaxf(m16[3], m16[7])));
        tmax = fmaxf(tmax, __shfl_xor(tmax, 32, 64));

        if (__any(tmax > mrun + 8.0f)) {
            const float mnew  = fmaxf(mrun, tmax);
            const float alpha = __builtin_amdgcn_exp2f(mrun - mnew);
            lrun *= alpha;
            #pragma unroll
            for (int r = 0; r < 16; ++r) { o0[r]*=alpha; o1[r]*=alpha; o2[r]*=alpha; o3[r]*=alpha; }
            mrun = mnew;
        }

        #pragma unroll
        for (int r = 0; r < 16; ++r) {   // exp in place: s becomes P
            s0[r] = __builtin_amdgcn_exp2f(s0[r] - mrun);
            s1[r] = __builtin_amdgcn_exp2f(s1[r] - mrun);
        }
        float ps = 0.f;
        #pragma unroll
        for (int r = 0; r < 16; ++r) ps += s0[r] + s1[r];
        lrun += ps;

        // P -> bf16 (S^T C/D reg order == PV B-slot order, verified bijection)
        bf16x8 pf0, pf1, pf2, pf3;
        #pragma unroll
        for (int e = 0; e < 8; ++e) {
            pf0[e] = (__bf16)s0[e]; pf1[e] = (__bf16)s0[8 + e];
            pf2[e] = (__bf16)s1[e]; pf3[e] = (__bf16)s1[8 + e];
        }

        // ---- PV: O^T[dv][q] += V^T[dv][kv] * P^T[kv][q]
        __builtin_amdgcn_s_setprio(1);
        #pragma unroll
        for (int bb = 0; bb < 4; ++bb) {
            const __bf16* vb = &vlds[cur][(bb * 32 + l31) * 64];
            f32x16& oo = (bb == 0) ? o0 : (bb == 1) ? o1 : (bb == 2) ? o2 : o3;
            #define PVSTEP(mm, pf)                                                \
            {                                                                     \
                bf16x4 a0 = *(const bf16x4*)(vb + (((2*(mm))   ^ vkey) << 3) + 4*g);\
                bf16x4 a1 = *(const bf16x4*)(vb + (((2*(mm)+1) ^ vkey) << 3) + 4*g);\
                bf16x8 va;                                                        \
                va[0]=a0[0]; va[1]=a0[1]; va[2]=a0[2]; va[3]=a0[3];               \
                va[4]=a1[0]; va[5]=a1[1]; va[6]=a1[2]; va[7]=a1[3];               \
                oo = __builtin_amdgcn_mfma_f32_32x32x16_bf16(va, pf, oo, 0, 0, 0);\
            }
            PVSTEP(0, pf0) PVSTEP(1, pf1) PVSTEP(2, pf2) PVSTEP(3, pf3)
            #undef PVSTEP
        }
        __builtin_amdgcn_s_setprio(0);

        if (tt + 1 < NCH) sync_all();
    }

    // ---- epilogue: unnormalized O' + (m,l) to workspace
    const float ltot  = lrun + __shfl_xor(lrun, 32, 64);
    const int   rowid = q * 16 + h;

    float* orow = wsO + ((size_t)sp * NROWS + rowid) * 128;
    #pragma unroll
    for (int bb = 0; bb < 4; ++bb) {
        const f32x16& oo = (bb == 0) ? o0 : (bb == 1) ? o1 : (bb == 2) ? o2 : o3;
        #pragma unroll
        for (int jj = 0; jj < 4; ++jj) {
            f32x4 v;
            v[0] = oo[4*jj+0]; v[1] = oo[4*jj+1]; v[2] = oo[4*jj+2]; v[3] = oo[4*jj+3];
            *(f32x4*)(orow + bb * 32 + 8 * jj + 4 * g) = v;
        }
    }
    if (lane < 32) {
        float* ml = wsML + ((size_t)sp * NROWS + rowid) * 2;
        ml[0] = mrun;
        ml[1] = ltot;
    }
}

// ---------------------------------------------------------------------------
// Combine: O[row] = sum_s 2^(m_s - M) * O'_s[row] / L.
// ---------------------------------------------------------------------------
__global__ __launch_bounds__(256, 4)
void fmha_combine(const float* __restrict__ wsO, const float* __restrict__ wsML,
                  float* __restrict__ Og)
{
    const int tid   = threadIdx.x;
    const int rowid = blockIdx.x * 8 + (tid >> 5);
    const int c     = (tid & 31) * 4;

    float m[NSPLIT], l[NSPLIT];
    float M = -1e30f;
    #pragma unroll
    for (int s = 0; s < NSPLIT; ++s) {
        const float* ml = wsML + ((size_t)s * NROWS + rowid) * 2;
        m[s] = ml[0]; l[s] = ml[1];
        M = fmaxf(M, m[s]);
    }
    float L = 0.f, w[NSPLIT];
    #pragma unroll
    for (int s = 0; s < NSPLIT; ++s) {
        w[s] = __builtin_amdgcn_exp2f(m[s] - M);
        L += l[s] * w[s];
    }
    const float inv = 1.0f / L;

    f32x4 acc; acc[0]=0.f; acc[1]=0.f; acc[2]=0.f; acc[3]=0.f;
    #pragma unroll
    for (int s = 0; s < NSPLIT; ++s) {
        f32x4 v = *(const f32x4*)(wsO + ((size_t)s * NROWS + rowid) * 128 + c);
        acc[0] += v[0] * w[s]; acc[1] += v[1] * w[s];
        acc[2] += v[2] * w[s]; acc[3] += v[3] * w[s];
    }
    f32x4 r;
    r[0] = acc[0]*inv; r[1] = acc[1]*inv; r[2] = acc[2]*inv; r[3] = acc[3]*inv;
    *(f32x4*)(Og + (size_t)rowid * 128 + c) = r;
}

// ---------------------------------------------------------------------------
// Fallback (ws too small — not expected): R1-style single-pass kernel.
// ---------------------------------------------------------------------------
__global__ __launch_bounds__(256, 2)
void fmha_fb(const float* __restrict__ Qg, const float* __restrict__ Kg,
             const float* __restrict__ Vg, float* __restrict__ Og)
{
    __shared__ __align__(16) __bf16 klds[2][32 * 128];
    __shared__ __align__(16) __bf16 vtlds[2][DH * 36];

    const int tid  = threadIdx.x;
    const int lane = tid & 63;
    const int wrp  = tid >> 6;
    const int g    = lane >> 5;
    const int l31  = lane & 31;

    const int b    = blockIdx.x;
    const int h    = 2 * (b & 7) + ((b >> 3) >> 4);
    const int qblk = (b >> 3) & 15;

    const float qscale = 1.4426950408889634f * 0.08838834764831845f;
    const int q = qblk * 128 + wrp * 32 + l31;

    bf16x8 qf[8];
    {
        const float* qrow = Qg + (size_t)q * HD + h * DH;
        #pragma unroll
        for (int db = 0; db < 8; ++db) {
            f32x4 a = *(const f32x4*)(qrow + db * 16 + 8 * g);
            f32x4 c = *(const f32x4*)(qrow + db * 16 + 8 * g + 4);
            bf16x8 f;
            f[0] = (__bf16)(a[0] * qscale); f[1] = (__bf16)(a[1] * qscale);
            f[2] = (__bf16)(a[2] * qscale); f[3] = (__bf16)(a[3] * qscale);
            f[4] = (__bf16)(c[0] * qscale); f[5] = (__bf16)(c[1] * qscale);
            f[6] = (__bf16)(c[2] * qscale); f[7] = (__bf16)(c[3] * qscale);
            qf[db] = f;
        }
    }

    const int krow = tid >> 3, kc = tid & 7;
    const int vkv  = tid & 31, vdv0 = (tid >> 5) * 16;
    const float* kbase = Kg + (size_t)h * DH;
    const float* vbase = Vg + (size_t)h * DH;

    f32x4 kreg0, kreg1, kreg2, kreg3, vreg0, vreg1, vreg2, vreg3;

    auto stage_load = [&](int t) {
        const float* kp = kbase + (size_t)(t * 32 + krow) * HD + kc * 8;
        kreg0 = *(const f32x4*)(kp);
        kreg1 = *(const f32x4*)(kp + 4);
        kreg2 = *(const f32x4*)(kp + 64);
        kreg3 = *(const f32x4*)(kp + 68);
        const float* vp = vbase + (size_t)(t * 32 + vkv) * HD + vdv0;
        vreg0 = *(const f32x4*)(vp);
        vreg1 = *(const f32x4*)(vp + 4);
        vreg2 = *(const f32x4*)(vp + 8);
        vreg3 = *(const f32x4*)(vp + 12);
    };

    auto stage_write = [&](int buf) {
        bf16x8 k0, k1;
        k0[0]=(__bf16)kreg0[0]; k0[1]=(__bf16)kreg0[1]; k0[2]=(__bf16)kreg0[2]; k0[3]=(__bf16)kreg0[3];
        k0[4]=(__bf16)kreg1[0]; k0[5]=(__bf16)kreg1[1]; k0[6]=(__bf16)kreg1[2]; k0[7]=(__bf16)kreg1[3];
        k1[0]=(__bf16)kreg2[0]; k1[1]=(__bf16)kreg2[1]; k1[2]=(__bf16)kreg2[2]; k1[3]=(__bf16)kreg2[3];
        k1[4]=(__bf16)kreg3[0]; k1[5]=(__bf16)kreg3[1]; k1[6]=(__bf16)kreg3[2]; k1[7]=(__bf16)kreg3[3];
        const int swz = (krow & 7) << 3;
        *(bf16x8*)&klds[buf][krow * 128 + ((kc * 8) ^ swz)]      = k0;
        *(bf16x8*)&klds[buf][krow * 128 + ((kc * 8 + 64) ^ swz)] = k1;
        #pragma unroll
        for (int jj = 0; jj < 4; ++jj) {
            f32x4 vv = (jj == 0) ? vreg0 : (jj == 1) ? vreg1 : (jj == 2) ? vreg2 : vreg3;
            #pragma unroll
            for (int e = 0; e < 4; ++e)
                vtlds[buf][(vdv0 + jj * 4 + e) * 36 + vkv] = (__bf16)vv[e];
        }
    };

    float mrun = -1e30f, lrun = 0.0f;
    f32x16 o0, o1, o2, o3;
    #pragma unroll
    for (int r = 0; r < 16; ++r) { o0[r] = 0.f; o1[r] = 0.f; o2[r] = 0.f; o3[r] = 0.f; }

    stage_load(0);
    stage_write(0);

    for (int tt = 0; tt < 64; ++tt) {
        const int cur = tt & 1;
        if (tt + 1 < 64) stage_load(tt + 1);
        __syncthreads();

        f32x16 sa, sb;
        #pragma unroll
        for (int r = 0; r < 16; ++r) { sa[r] = 0.f; sb[r] = 0.f; }
        const int kswz = (l31 & 7) << 3;
        #pragma unroll
        for (int db = 0; db < 4; ++db) {
            bf16x8 kfa = *(const bf16x8*)&klds[cur][l31 * 128 + (((2*db)   * 16 + g * 8) ^ kswz)];
            sa = __builtin_amdgcn_mfma_f32_32x32x16_bf16(kfa, qf[2*db],   sa, 0, 0, 0);
            bf16x8 kfb = *(const bf16x8*)&klds[cur][l31 * 128 + (((2*db+1) * 16 + g * 8) ^ kswz)];
            sb = __builtin_amdgcn_mfma_f32_32x32x16_bf16(kfb, qf[2*db+1], sb, 0, 0, 0);
        }
        f32x16 s;
        #pragma unroll
        for (int r = 0; r < 16; ++r) s[r] = sa[r] + sb[r];

        float m8[8];
        #pragma unroll
        for (int r = 0; r < 8; ++r) m8[r] = fmaxf(s[r], s[r + 8]);
        float tmax = fmaxf(fmaxf(fmaxf(m8[0], m8[4]), fmaxf(m8[1], m8[5])),
                           fmaxf(fmaxf(m8[2], m8[6]), fmaxf(m8[3], m8[7])));
        tmax = fmaxf(tmax, __shfl_xor(tmax, 32, 64));

        if (__any(tmax > mrun + 8.0f)) {
            const float mnew  = fmaxf(mrun, tmax);
            const float alpha = __builtin_amdgcn_exp2f(mrun - mnew);
            lrun *= alpha;
            #pragma unroll
            for (int r = 0; r < 16; ++r) { o0[r] *= alpha; o1[r] *= alpha; o2[r] *= alpha; o3[r] *= alpha; }
            mrun = mnew;
        }

        float p[16];
        #pragma unroll
        for (int r = 0; r < 16; ++r) p[r] = __builtin_amdgcn_exp2f(s[r] - mrun);
        float ps0 = 0, ps1 = 0, ps2 = 0, ps3 = 0;
        #pragma unroll
        for (int r = 0; r < 4; ++r) { ps0 += p[r]; ps1 += p[r+4]; ps2 += p[r+8]; ps3 += p[r+12]; }
        lrun += ((ps0 + ps1) + (ps2 + ps3));

        bf16x8 pf0, pf1;
        #pragma unroll
        for (int e = 0; e < 8; ++e) { pf0[e] = (__bf16)p[e]; pf1[e] = (__bf16)p[8 + e]; }

        #pragma unroll
        for (int bb = 0; bb < 4; ++bb) {
            const __bf16* vb = &vtlds[cur][(bb * 32 + l31) * 36];
            bf16x4 a0 = *(const bf16x4*)(vb + 4 * g);
            bf16x4 a1 = *(const bf16x4*)(vb + 8 + 4 * g);
            bf16x8 va;
            va[0]=a0[0]; va[1]=a0[1]; va[2]=a0[2]; va[3]=a0[3];
            va[4]=a1[0]; va[5]=a1[1]; va[6]=a1[2]; va[7]=a1[3];
            f32x16& oo = (bb == 0) ? o0 : (bb == 1) ? o1 : (bb == 2) ? o2 : o3;
            oo = __builtin_amdgcn_mfma_f32_32x32x16_bf16(va, pf0, oo, 0, 0, 0);
            bf16x4 b0 = *(const bf16x4*)(vb + 16 + 4 * g);
            bf16x4 b1 = *(const bf16x4*)(vb + 24 + 4 * g);
            va[0]=b0[0]; va[1]=b0[1]; va[2]=b0[2]; va[3]=b0[3];
            va[4]=b1[0]; va[5]=b1[1]; va[6]=b1[2]; va[7]=b1[3];
            oo = __builtin_amdgcn_mfma_f32_32x32x16_bf16(va, pf1, oo, 0, 0, 0);
        }

        if (tt + 1 < 64) stage_write(cur ^ 1);
    }

    const float ltot = lrun + __shfl_xor(lrun, 32, 64);
    const float inv  = 1.0f / ltot;
    float* orow = Og + ((size_t)q * 16 + h) * 128;
    #pragma unroll
    for (int bb = 0; bb < 4; ++bb) {
        const f32x16& oo = (bb == 0) ? o0 : (bb == 1) ? o1 : (bb == 2) ? o2 : o3;
        #pragma unroll
        for (int jj = 0; jj < 4; ++jj) {
            f32x4 v;
            v[0] = oo[4*jj+0] * inv; v[1] = oo[4*jj+1] * inv;
            v[2] = oo[4*jj+2] * inv; v[3] = oo[4*jj+3] * inv;
            *(f32x4*)(orow + bb * 32 + 8 * jj + 4 * g) = v;
        }
    }
}

extern "C" void kernel_launch(void* const* d_in, const int* in_sizes, int n_in,
                              void* d_out, int out_size, void* d_ws, size_t ws_size,
                              hipStream_t stream) {
    const float* Q = (const float*)d_in[0];
    const float* K = (const float*)d_in[1];
    const float* V = (const float*)d_in[2];
    float* O = (float*)d_out;

    const size_t kv_bytes = (size_t)512 * TILE_ELEMS * 2;   // 8 MB each (16h x 32T x 16KB)
    const size_t needO  = (size_t)NSPLIT * NROWS * 128;     // floats (32 MB)
    const size_t needML = (size_t)NSPLIT * NROWS * 2;       // floats
    const size_t need_bytes = 2 * kv_bytes + (needO + needML) * sizeof(float);

    if (ws_size >= need_bytes) {
        __bf16* wsK = (__bf16*)d_ws;
        __bf16* wsV = (__bf16*)((char*)d_ws + kv_bytes);
        float*  wsO = (float*)((char*)d_ws + 2 * kv_bytes);
        float*  wsML = wsO + needO;
        hipLaunchKernelGGL(prep_k,  dim3(2048), dim3(256), 0, stream, K, wsK);
        hipLaunchKernelGGL(prep_vt, dim3(4096), dim3(256), 0, stream, V, wsV);
        hipLaunchKernelGGL(fmha_main, dim3(512), dim3(256), 0, stream,
                           Q, wsK, wsV, wsO, wsML);
        hipLaunchKernelGGL(fmha_combine, dim3(NROWS / 8), dim3(256), 0, stream,
                           wsO, wsML, O);
    } else {
        hipLaunchKernelGGL(fmha_fb, dim3(256), dim3(256), 0, stream, Q, K, V, O);
    }
}